// Round 19
// baseline (237.446 us; speedup 1.0000x reference)
//
#include <hip/hip_runtime.h>

#define IN_DIM 256
#define EMB 128
// bucket = dst >> 9 (512 nodes per bucket). Requires N <= 131072 (src packed in 17 bits).
#define BKT_SHIFT 9
#define BKT_NODES 512
#define BINE 2048       // edges per bin_scatter block (782 blocks -> ~3/CU)
#define SCAP 12288      // per-bucket region capacity (mean ~8192, +45 sigma)

typedef __attribute__((ext_vector_type(8))) short short8;
typedef __attribute__((ext_vector_type(4))) float f32x4;

__device__ __forceinline__ unsigned short bf16rtne(float f) {
    unsigned int u = __float_as_uint(f);
    return (unsigned short)((u + 0x7fffu + ((u >> 16) & 1u)) >> 16);
}

__device__ __forceinline__ unsigned int packbf2(float lo, float hi) {
    return ((unsigned int)bf16rtne(hi) << 16) | (unsigned int)bf16rtne(lo);
}

// packed f32x8 -> bf16x8 via native cvt_pk (RNE)
__device__ __forceinline__ short8 pack8(float4 f0, float4 f1) {
    union { uint4 u; short8 s; } U;
    asm("v_cvt_pk_bf16_f32 %0, %1, %2" : "=v"(U.u.x) : "v"(f0.x), "v"(f0.y));
    asm("v_cvt_pk_bf16_f32 %0, %1, %2" : "=v"(U.u.y) : "v"(f0.z), "v"(f0.w));
    asm("v_cvt_pk_bf16_f32 %0, %1, %2" : "=v"(U.u.z) : "v"(f1.x), "v"(f1.y));
    asm("v_cvt_pk_bf16_f32 %0, %1, %2" : "=v"(U.u.w) : "v"(f1.z), "v"(f1.w));
    return U.s;
}

// ---------------- CSR build stage 1: bin edges into fixed-capacity bucket regions ----
// Per-bucket cursors start at 0 (memset); each block reserves ranges with one
// atomicAdd per bucket. Block 0 also casts W^T to bf16. LDS-staged, streams
// contiguous runs out. BINE=2048/512thr: short critical path, 3 blocks/CU.

__global__ __launch_bounds__(512) void bin_scatter(const int* __restrict__ src,
                                                   const int* __restrict__ dst,
                                                   const float* __restrict__ w,
                                                   int* __restrict__ gcursor,
                                                   int2* __restrict__ binned, int E,
                                                   const float* __restrict__ W,
                                                   unsigned short* __restrict__ wtg) {
    __shared__ int h[256];
    __shared__ int lbase[256];
    __shared__ int gbase[256];
    __shared__ int lcur[256];
    __shared__ int2 stage[BINE];         // 16 KB
    __shared__ unsigned char sb[BINE];   // 2 KB
    int t = threadIdx.x;

    // W^T cast in block 0 (32768 elems, 64/thread)
    if (blockIdx.x == 0) {
        for (int i = t; i < IN_DIM * EMB; i += 512) {
            int c = i & 127;
            int k = i >> 7;
            wtg[c * 256 + k] = bf16rtne(W[(size_t)k * 128 + c]);
        }
    }

    int e0 = blockIdx.x * BINE;
    int e1 = min(E, e0 + BINE);
    int n = e1 - e0;

    int ed[4], es[4];
    float ewv[4];
    if (n == BINE) {
        // branch-free: all 12 loads issue unguarded, stay in flight
#pragma unroll
        for (int j = 0; j < 4; ++j) {
            int i = e0 + t + j * 512;
            ed[j] = dst[i];
            es[j] = src[i];
            ewv[j] = w[i];
        }
    } else {
#pragma unroll
        for (int j = 0; j < 4; ++j) {
            int i = e0 + t + j * 512;
            if (i < e1) {
                ed[j] = dst[i];
                es[j] = src[i];
                ewv[j] = w[i];
            } else
                ed[j] = -1;
        }
    }
    if (t < 256) h[t] = 0;
    __syncthreads();
#pragma unroll
    for (int j = 0; j < 4; ++j)
        if (ed[j] >= 0) atomicAdd(&h[ed[j] >> BKT_SHIFT], 1);
    __syncthreads();
    int v = 0;
    if (t < 256) {
        v = h[t];
        lbase[t] = v;
    }
    __syncthreads();
    for (int off = 1; off < 256; off <<= 1) {
        int u = 0;
        if (t < 256 && t >= off) u = lbase[t - off];
        __syncthreads();
        if (t < 256) lbase[t] += u;
        __syncthreads();
    }
    if (t < 256) {
        lbase[t] -= v;  // exclusive
        lcur[t] = lbase[t];
        gbase[t] = v ? atomicAdd(&gcursor[t], v) : 0;
    }
    __syncthreads();
#pragma unroll
    for (int j = 0; j < 4; ++j) {
        if (ed[j] >= 0) {
            int b = ed[j] >> BKT_SHIFT;
            int p = atomicAdd(&lcur[b], 1);
            int2 r;
            r.x = es[j] | ((ed[j] & (BKT_NODES - 1)) << 17);
            r.y = __float_as_int(ewv[j]);
            stage[p] = r;
            sb[p] = (unsigned char)b;
        }
    }
    __syncthreads();
    // stream out: run of bucket b -> binned[b*SCAP + gbase[b] + (i - lbase[b])]
    for (int i = t; i < n; i += 512) {
        int b = sb[i];
        int pos = gbase[b] + (i - lbase[b]);
        if (pos < SCAP) binned[(size_t)b * SCAP + pos] = stage[i];
    }
}

// ---------------- CSR build stage 2: per-bucket counting sort + inline global scan ----

__global__ __launch_bounds__(1024) void bucket_sort(const int2* __restrict__ binned,
                                                    const int* __restrict__ counts,
                                                    int2* __restrict__ sorted,
                                                    int* __restrict__ row_ptr,
                                                    int N, int E, int NB) {
    __shared__ int cnt[BKT_NODES];
    __shared__ int cur[BKT_NODES];
    __shared__ int scn[BKT_NODES];
    __shared__ int sc[256];
    __shared__ int begS, nS;
    __shared__ int2 stage[SCAP];  // 96 KB
    int t = threadIdx.x;
    int b = blockIdx.x;
    int node0 = b << BKT_SHIFT;
    int nn = min(BKT_NODES, N - node0);

    // inclusive scan of bucket counts (first 256 threads)
    if (t < 256) sc[t] = (t < NB) ? min(counts[t], SCAP) : 0;
    __syncthreads();
    for (int off = 1; off < 256; off <<= 1) {
        int u = 0;
        if (t < 256 && t >= off) u = sc[t - off];
        __syncthreads();
        if (t < 256) sc[t] += u;
        __syncthreads();
    }
    if (t == 0) {
        int cb = min(counts[b], SCAP);
        begS = sc[b] - cb;
        nS = cb;
        if (b == 0) row_ptr[N] = E;
    }
    __syncthreads();
    int beg = begS;
    int n = nS;

    if (t < BKT_NODES) cnt[t] = 0;
    __syncthreads();
    const int2* bsrc = binned + (size_t)b * SCAP;
    for (int i = t; i < n; i += 1024) {
        int ld = ((unsigned int)bsrc[i].x) >> 17;
        atomicAdd(&cnt[ld], 1);
    }
    __syncthreads();
    int v = 0;
    if (t < BKT_NODES) {
        v = cnt[t];
        scn[t] = v;
    }
    __syncthreads();
    for (int off = 1; off < BKT_NODES; off <<= 1) {
        int u = 0;
        if (t < BKT_NODES && t >= off) u = scn[t - off];
        __syncthreads();
        if (t < BKT_NODES) scn[t] += u;
        __syncthreads();
    }
    if (t < BKT_NODES) {
        int excl = scn[t] - v;
        cur[t] = excl;
        if (t < nn) row_ptr[node0 + t] = beg + excl;
    }
    __syncthreads();
    for (int i = t; i < n; i += 1024) {
        int2 r = bsrc[i];
        int ld = ((unsigned int)r.x) >> 17;
        int p = atomicAdd(&cur[ld], 1);
        r.x &= 0x1FFFF;
        stage[p] = r;
    }
    __syncthreads();
    for (int i = t; i < n; i += 1024) sorted[beg + i] = stage[i];  // sequential
}

// ---------------- MFMA GEMM: h = relu(x@W + b), x f32 read directly ----------------

__global__ __launch_bounds__(256) void gemm_mfma(const float* __restrict__ x,
                                                 const unsigned short* __restrict__ wtg,
                                                 const float* __restrict__ bias,
                                                 unsigned short* __restrict__ hbf, int N) {
    __shared__ float Asf[128][64];          // 32 KB
    __shared__ unsigned short Bs[128][64];  // 16 KB
    int tid = threadIdx.x;
    int wv = tid >> 6;
    int lane = tid & 63;
    int lr = lane & 15;
    int lg = lane >> 4;
    int wr = wv * 32;
    int row0 = blockIdx.x * 128;

    f32x4 acc[2][8];
#pragma unroll
    for (int m = 0; m < 2; ++m)
#pragma unroll
        for (int n = 0; n < 8; ++n) acc[m][n] = (f32x4){0.f, 0.f, 0.f, 0.f};

    for (int kb = 0; kb < IN_DIM; kb += 64) {
#pragma unroll
        for (int i = 0; i < 8; ++i) {
            int p = 256 * i + wv * 64 + lane;
            int r = p >> 4;
            int c = p & 15;
            int gr = row0 + r;
            if (gr >= N) gr = N - 1;
            const float* ga = x + (size_t)gr * IN_DIM + kb + ((c ^ (r & 7)) << 2);
            __builtin_amdgcn_global_load_lds(
                (const __attribute__((address_space(1))) void*)ga,
                (__attribute__((address_space(3))) void*)((char*)&Asf[0][0] + (size_t)(256 * i + wv * 64) * 16),
                16, 0, 0);
        }
#pragma unroll
        for (int i = 0; i < 4; ++i) {
            int p = 256 * i + wv * 64 + lane;
            int r = p >> 3;
            int c = p & 7;
            const unsigned short* gb = wtg + (size_t)r * IN_DIM + kb + ((c ^ (r & 7)) * 8);
            __builtin_amdgcn_global_load_lds(
                (const __attribute__((address_space(1))) void*)gb,
                (__attribute__((address_space(3))) void*)((char*)&Bs[0][0] + (size_t)(256 * i + wv * 64) * 16),
                16, 0, 0);
        }
        __syncthreads();

        short8 a[2][2];
#pragma unroll
        for (int m = 0; m < 2; ++m)
#pragma unroll
            for (int kk = 0; kk < 2; ++kk) {
                int r = wr + m * 16 + lr;
                int s = r & 7;
                int ch0 = kk * 8 + lg * 2;
                float4 f0 = *(const float4*)&Asf[r][(ch0 ^ s) << 2];
                float4 f1 = *(const float4*)&Asf[r][((ch0 + 1) ^ s) << 2];
                a[m][kk] = pack8(f0, f1);
            }
#pragma unroll
        for (int n = 0; n < 8; ++n) {
            int cc = n * 16 + lr;
            int sw = cc & 7;
            short8 b0 = *(const short8*)&Bs[cc][(((0 * 4 + lg) ^ sw) * 8)];
            short8 b1 = *(const short8*)&Bs[cc][(((1 * 4 + lg) ^ sw) * 8)];
            acc[0][n] = __builtin_amdgcn_mfma_f32_16x16x32_bf16(a[0][0], b0, acc[0][n], 0, 0, 0);
            acc[0][n] = __builtin_amdgcn_mfma_f32_16x16x32_bf16(a[0][1], b1, acc[0][n], 0, 0, 0);
            acc[1][n] = __builtin_amdgcn_mfma_f32_16x16x32_bf16(a[1][0], b0, acc[1][n], 0, 0, 0);
            acc[1][n] = __builtin_amdgcn_mfma_f32_16x16x32_bf16(a[1][1], b1, acc[1][n], 0, 0, 0);
        }
        __syncthreads();
    }

#pragma unroll
    for (int n = 0; n < 8; ++n) {
        int c = n * 16 + lr;
        float bv = bias[c];
#pragma unroll
        for (int m = 0; m < 2; ++m) {
#pragma unroll
            for (int j = 0; j < 4; ++j) {
                int r = row0 + wr + m * 16 + lg * 4 + j;
                if (r < N) {
                    float v = fmaxf(acc[m][n][j] + bv, 0.f);
                    hbf[(size_t)r * EMB + c] = bf16rtne(v);
                }
            }
        }
    }
}

// ---------------- propagation: wave per node, readlane broadcasts, 16-deep gathers ----

template <int OUTBF>
__global__ __launch_bounds__(256) void prop_g(const unsigned int* __restrict__ hin,
                                              void* __restrict__ hout,
                                              const int* __restrict__ rp,
                                              const int2* __restrict__ rec, int N) {
    int wvid = threadIdx.x >> 6;
    int lane = threadIdx.x & 63;
    int node = blockIdx.x * 4 + wvid;
    if (node >= N) return;
    int beg = __builtin_amdgcn_readfirstlane(rp[node]);
    int end = __builtin_amdgcn_readfirstlane(rp[node + 1]);
    float ax = 0.f, ay = 0.f;
    for (int c0 = beg; c0 < end; c0 += 64) {
        int cnt = end - c0;
        if (cnt > 64) cnt = 64;
        int li = lane < cnt ? lane : 0;
        int2 r = rec[c0 + li];
        for (int jb = 0; jb < cnt; jb += 16) {
            int ssrc[16];
            float sw[16];
#pragma unroll
            for (int k = 0; k < 16; ++k) {
                int jj = jb + k;
                int jc = jj < cnt ? jj : 0;
                ssrc[k] = __builtin_amdgcn_readlane(r.x, jc);
                float wv = __uint_as_float((unsigned int)__builtin_amdgcn_readlane(r.y, jc));
                sw[k] = (jj < cnt) ? wv : 0.f;
            }
            unsigned int g[16];
#pragma unroll
            for (int k = 0; k < 16; ++k) g[k] = hin[(size_t)ssrc[k] * 64 + lane];
#pragma unroll
            for (int k = 0; k < 16; ++k) {
                ax = fmaf(sw[k], __uint_as_float(g[k] << 16), ax);
                ay = fmaf(sw[k], __uint_as_float(g[k] & 0xffff0000u), ay);
            }
        }
    }
    if (OUTBF) {
        ((unsigned int*)hout)[(size_t)node * 64 + lane] = packbf2(ax, ay);
    } else {
        float2 o;
        o.x = ax;
        o.y = ay;
        ((float2*)hout)[(size_t)node * 64 + lane] = o;
    }
}

// ---------------- launch ----------------

extern "C" void kernel_launch(void* const* d_in, const int* in_sizes, int n_in,
                              void* d_out, int out_size, void* d_ws, size_t ws_size,
                              hipStream_t stream) {
    const float* x = (const float*)d_in[0];
    const float* W = (const float*)d_in[1];
    const float* b = (const float*)d_in[2];
    const int* esrc = (const int*)d_in[3];
    const int* edst = (const int*)d_in[4];
    const float* ew = (const float*)d_in[5];
    int N = in_sizes[0] / IN_DIM;
    int E = in_sizes[3];
    int NB = (N + BKT_NODES - 1) >> BKT_SHIFT;  // 196

    char* p = (char*)d_ws;
    auto alloc = [&](size_t bytes) -> void* {
        void* r = (void*)p;
        p += (bytes + 255) & ~(size_t)255;
        return r;
    };
    unsigned short* hbf = (unsigned short*)alloc((size_t)N * EMB * 2);
    unsigned short* h1bf = (unsigned short*)alloc((size_t)N * EMB * 2);
    unsigned short* wtg = (unsigned short*)alloc((size_t)IN_DIM * EMB * 2);
    int* gcursor = (int*)alloc(256 * 4);
    int* row_ptr = (int*)alloc((size_t)(N + 1) * 4);
    int2* binned = (int2*)alloc((size_t)NB * SCAP * 8);
    int2* sorted = (int2*)alloc((size_t)E * 8);

    hipMemsetAsync(gcursor, 0, 256 * 4, stream);
    bin_scatter<<<(E + BINE - 1) / BINE, 512, 0, stream>>>(esrc, edst, ew, gcursor, binned, E, W, wtg);
    bucket_sort<<<NB, 1024, 0, stream>>>(binned, gcursor, sorted, row_ptr, N, E, NB);

    gemm_mfma<<<(N + 127) / 128, 256, 0, stream>>>(x, wtg, b, hbf, N);
    prop_g<1><<<(N + 3) / 4, 256, 0, stream>>>((const unsigned int*)hbf, h1bf, row_ptr, sorted, N);
    prop_g<0><<<(N + 3) / 4, 256, 0, stream>>>((const unsigned int*)h1bf, d_out, row_ptr, sorted, N);
}

// Round 20
// 233.676 us; speedup vs baseline: 1.0161x; 1.0161x over previous
//
#include <hip/hip_runtime.h>

#define IN_DIM 256
#define EMB 128
// bucket = dst >> 9 (512 nodes per bucket). Requires N <= 131072 (src packed in 17 bits).
#define BKT_SHIFT 9
#define BKT_NODES 512
#define BINE 2048       // edges per bin_scatter block; 256 thr -> 8 blocks/CU
#define SCAP 12288      // per-bucket region capacity (mean ~8192, +45 sigma)

typedef __attribute__((ext_vector_type(8))) short short8;
typedef __attribute__((ext_vector_type(4))) float f32x4;

__device__ __forceinline__ unsigned short bf16rtne(float f) {
    unsigned int u = __float_as_uint(f);
    return (unsigned short)((u + 0x7fffu + ((u >> 16) & 1u)) >> 16);
}

__device__ __forceinline__ unsigned int packbf2(float lo, float hi) {
    return ((unsigned int)bf16rtne(hi) << 16) | (unsigned int)bf16rtne(lo);
}

// packed f32x8 -> bf16x8 via native cvt_pk (RNE)
__device__ __forceinline__ short8 pack8(float4 f0, float4 f1) {
    union { uint4 u; short8 s; } U;
    asm("v_cvt_pk_bf16_f32 %0, %1, %2" : "=v"(U.u.x) : "v"(f0.x), "v"(f0.y));
    asm("v_cvt_pk_bf16_f32 %0, %1, %2" : "=v"(U.u.y) : "v"(f0.z), "v"(f0.w));
    asm("v_cvt_pk_bf16_f32 %0, %1, %2" : "=v"(U.u.z) : "v"(f1.x), "v"(f1.y));
    asm("v_cvt_pk_bf16_f32 %0, %1, %2" : "=v"(U.u.w) : "v"(f1.z), "v"(f1.w));
    return U.s;
}

// ---------------- CSR build stage 1: bin edges into fixed-capacity bucket regions ----
// STAGING-FREE: {branch-free loads -> LDS hist -> 1 global atomic/bucket
// reserving a contiguous run -> direct global write at gbase[b]+local_slot}.
// No scan, no LDS record staging, 3 barriers. 3 KB LDS -> 8 blocks/CU.

__global__ __launch_bounds__(256) void bin_scatter(const int* __restrict__ src,
                                                   const int* __restrict__ dst,
                                                   const float* __restrict__ w,
                                                   int* __restrict__ gcursor,
                                                   int2* __restrict__ binned, int E,
                                                   const float* __restrict__ W,
                                                   unsigned short* __restrict__ wtg) {
    __shared__ int h[256];
    __shared__ int gbase[256];
    __shared__ int lcur[256];
    int t = threadIdx.x;

    // W^T cast in block 0 (32768 elems, 128/thread)
    if (blockIdx.x == 0) {
        for (int i = t; i < IN_DIM * EMB; i += 256) {
            int c = i & 127;
            int k = i >> 7;
            wtg[c * 256 + k] = bf16rtne(W[(size_t)k * 128 + c]);
        }
    }

    int e0 = blockIdx.x * BINE;
    int e1 = min(E, e0 + BINE);
    int n = e1 - e0;

    int ed[8], es[8];
    float ewv[8];
    if (n == BINE) {
        // branch-free: all 24 loads issue unguarded, stay in flight
#pragma unroll
        for (int j = 0; j < 8; ++j) {
            int i = e0 + t + j * 256;
            ed[j] = dst[i];
            es[j] = src[i];
            ewv[j] = w[i];
        }
    } else {
#pragma unroll
        for (int j = 0; j < 8; ++j) {
            int i = e0 + t + j * 256;
            if (i < e1) {
                ed[j] = dst[i];
                es[j] = src[i];
                ewv[j] = w[i];
            } else
                ed[j] = -1;
        }
    }
    h[t] = 0;
    lcur[t] = 0;
    __syncthreads();
#pragma unroll
    for (int j = 0; j < 8; ++j)
        if (ed[j] >= 0) atomicAdd(&h[ed[j] >> BKT_SHIFT], 1);
    __syncthreads();
    int v = h[t];
    gbase[t] = v ? atomicAdd(&gcursor[t], v) : 0;
    __syncthreads();
    // place: local slot from LDS cursor, direct global write into the run
#pragma unroll
    for (int j = 0; j < 8; ++j) {
        if (ed[j] >= 0) {
            int b = ed[j] >> BKT_SHIFT;
            int p = gbase[b] + atomicAdd(&lcur[b], 1);
            if (p < SCAP) {
                int2 r;
                r.x = es[j] | ((ed[j] & (BKT_NODES - 1)) << 17);
                r.y = __float_as_int(ewv[j]);
                binned[(size_t)b * SCAP + p] = r;
            }
        }
    }
}

// ---------------- CSR build stage 2: per-bucket counting sort + inline global scan ----

__global__ __launch_bounds__(1024) void bucket_sort(const int2* __restrict__ binned,
                                                    const int* __restrict__ counts,
                                                    int2* __restrict__ sorted,
                                                    int* __restrict__ row_ptr,
                                                    int N, int E, int NB) {
    __shared__ int cnt[BKT_NODES];
    __shared__ int cur[BKT_NODES];
    __shared__ int scn[BKT_NODES];
    __shared__ int sc[256];
    __shared__ int begS, nS;
    __shared__ int2 stage[SCAP];  // 96 KB
    int t = threadIdx.x;
    int b = blockIdx.x;
    int node0 = b << BKT_SHIFT;
    int nn = min(BKT_NODES, N - node0);

    // inclusive scan of bucket counts (first 256 threads)
    if (t < 256) sc[t] = (t < NB) ? min(counts[t], SCAP) : 0;
    __syncthreads();
    for (int off = 1; off < 256; off <<= 1) {
        int u = 0;
        if (t < 256 && t >= off) u = sc[t - off];
        __syncthreads();
        if (t < 256) sc[t] += u;
        __syncthreads();
    }
    if (t == 0) {
        int cb = min(counts[b], SCAP);
        begS = sc[b] - cb;
        nS = cb;
        if (b == 0) row_ptr[N] = E;
    }
    __syncthreads();
    int beg = begS;
    int n = nS;

    if (t < BKT_NODES) cnt[t] = 0;
    __syncthreads();
    const int2* bsrc = binned + (size_t)b * SCAP;
    for (int i = t; i < n; i += 1024) {
        int ld = ((unsigned int)bsrc[i].x) >> 17;
        atomicAdd(&cnt[ld], 1);
    }
    __syncthreads();
    int v = 0;
    if (t < BKT_NODES) {
        v = cnt[t];
        scn[t] = v;
    }
    __syncthreads();
    for (int off = 1; off < BKT_NODES; off <<= 1) {
        int u = 0;
        if (t < BKT_NODES && t >= off) u = scn[t - off];
        __syncthreads();
        if (t < BKT_NODES) scn[t] += u;
        __syncthreads();
    }
    if (t < BKT_NODES) {
        int excl = scn[t] - v;
        cur[t] = excl;
        if (t < nn) row_ptr[node0 + t] = beg + excl;
    }
    __syncthreads();
    for (int i = t; i < n; i += 1024) {
        int2 r = bsrc[i];
        int ld = ((unsigned int)r.x) >> 17;
        int p = atomicAdd(&cur[ld], 1);
        r.x &= 0x1FFFF;
        stage[p] = r;
    }
    __syncthreads();
    for (int i = t; i < n; i += 1024) sorted[beg + i] = stage[i];  // sequential
}

// ---------------- MFMA GEMM: h = relu(x@W + b), x f32 read directly ----------------

__global__ __launch_bounds__(256) void gemm_mfma(const float* __restrict__ x,
                                                 const unsigned short* __restrict__ wtg,
                                                 const float* __restrict__ bias,
                                                 unsigned short* __restrict__ hbf, int N) {
    __shared__ float Asf[128][64];          // 32 KB
    __shared__ unsigned short Bs[128][64];  // 16 KB
    int tid = threadIdx.x;
    int wv = tid >> 6;
    int lane = tid & 63;
    int lr = lane & 15;
    int lg = lane >> 4;
    int wr = wv * 32;
    int row0 = blockIdx.x * 128;

    f32x4 acc[2][8];
#pragma unroll
    for (int m = 0; m < 2; ++m)
#pragma unroll
        for (int n = 0; n < 8; ++n) acc[m][n] = (f32x4){0.f, 0.f, 0.f, 0.f};

    for (int kb = 0; kb < IN_DIM; kb += 64) {
#pragma unroll
        for (int i = 0; i < 8; ++i) {
            int p = 256 * i + wv * 64 + lane;
            int r = p >> 4;
            int c = p & 15;
            int gr = row0 + r;
            if (gr >= N) gr = N - 1;
            const float* ga = x + (size_t)gr * IN_DIM + kb + ((c ^ (r & 7)) << 2);
            __builtin_amdgcn_global_load_lds(
                (const __attribute__((address_space(1))) void*)ga,
                (__attribute__((address_space(3))) void*)((char*)&Asf[0][0] + (size_t)(256 * i + wv * 64) * 16),
                16, 0, 0);
        }
#pragma unroll
        for (int i = 0; i < 4; ++i) {
            int p = 256 * i + wv * 64 + lane;
            int r = p >> 3;
            int c = p & 7;
            const unsigned short* gb = wtg + (size_t)r * IN_DIM + kb + ((c ^ (r & 7)) * 8);
            __builtin_amdgcn_global_load_lds(
                (const __attribute__((address_space(1))) void*)gb,
                (__attribute__((address_space(3))) void*)((char*)&Bs[0][0] + (size_t)(256 * i + wv * 64) * 16),
                16, 0, 0);
        }
        __syncthreads();

        short8 a[2][2];
#pragma unroll
        for (int m = 0; m < 2; ++m)
#pragma unroll
            for (int kk = 0; kk < 2; ++kk) {
                int r = wr + m * 16 + lr;
                int s = r & 7;
                int ch0 = kk * 8 + lg * 2;
                float4 f0 = *(const float4*)&Asf[r][(ch0 ^ s) << 2];
                float4 f1 = *(const float4*)&Asf[r][((ch0 + 1) ^ s) << 2];
                a[m][kk] = pack8(f0, f1);
            }
#pragma unroll
        for (int n = 0; n < 8; ++n) {
            int cc = n * 16 + lr;
            int sw = cc & 7;
            short8 b0 = *(const short8*)&Bs[cc][(((0 * 4 + lg) ^ sw) * 8)];
            short8 b1 = *(const short8*)&Bs[cc][(((1 * 4 + lg) ^ sw) * 8)];
            acc[0][n] = __builtin_amdgcn_mfma_f32_16x16x32_bf16(a[0][0], b0, acc[0][n], 0, 0, 0);
            acc[0][n] = __builtin_amdgcn_mfma_f32_16x16x32_bf16(a[0][1], b1, acc[0][n], 0, 0, 0);
            acc[1][n] = __builtin_amdgcn_mfma_f32_16x16x32_bf16(a[1][0], b0, acc[1][n], 0, 0, 0);
            acc[1][n] = __builtin_amdgcn_mfma_f32_16x16x32_bf16(a[1][1], b1, acc[1][n], 0, 0, 0);
        }
        __syncthreads();
    }

#pragma unroll
    for (int n = 0; n < 8; ++n) {
        int c = n * 16 + lr;
        float bv = bias[c];
#pragma unroll
        for (int m = 0; m < 2; ++m) {
#pragma unroll
            for (int j = 0; j < 4; ++j) {
                int r = row0 + wr + m * 16 + lg * 4 + j;
                if (r < N) {
                    float v = fmaxf(acc[m][n][j] + bv, 0.f);
                    hbf[(size_t)r * EMB + c] = bf16rtne(v);
                }
            }
        }
    }
}

// ---------------- propagation: wave per node, readlane broadcasts, 16-deep gathers ----

template <int OUTBF>
__global__ __launch_bounds__(256) void prop_g(const unsigned int* __restrict__ hin,
                                              void* __restrict__ hout,
                                              const int* __restrict__ rp,
                                              const int2* __restrict__ rec, int N) {
    int wvid = threadIdx.x >> 6;
    int lane = threadIdx.x & 63;
    int node = blockIdx.x * 4 + wvid;
    if (node >= N) return;
    int beg = __builtin_amdgcn_readfirstlane(rp[node]);
    int end = __builtin_amdgcn_readfirstlane(rp[node + 1]);
    float ax = 0.f, ay = 0.f;
    for (int c0 = beg; c0 < end; c0 += 64) {
        int cnt = end - c0;
        if (cnt > 64) cnt = 64;
        int li = lane < cnt ? lane : 0;
        int2 r = rec[c0 + li];
        for (int jb = 0; jb < cnt; jb += 16) {
            int ssrc[16];
            float sw[16];
#pragma unroll
            for (int k = 0; k < 16; ++k) {
                int jj = jb + k;
                int jc = jj < cnt ? jj : 0;
                ssrc[k] = __builtin_amdgcn_readlane(r.x, jc);
                float wv = __uint_as_float((unsigned int)__builtin_amdgcn_readlane(r.y, jc));
                sw[k] = (jj < cnt) ? wv : 0.f;
            }
            unsigned int g[16];
#pragma unroll
            for (int k = 0; k < 16; ++k) g[k] = hin[(size_t)ssrc[k] * 64 + lane];
#pragma unroll
            for (int k = 0; k < 16; ++k) {
                ax = fmaf(sw[k], __uint_as_float(g[k] << 16), ax);
                ay = fmaf(sw[k], __uint_as_float(g[k] & 0xffff0000u), ay);
            }
        }
    }
    if (OUTBF) {
        ((unsigned int*)hout)[(size_t)node * 64 + lane] = packbf2(ax, ay);
    } else {
        float2 o;
        o.x = ax;
        o.y = ay;
        ((float2*)hout)[(size_t)node * 64 + lane] = o;
    }
}

// ---------------- launch ----------------

extern "C" void kernel_launch(void* const* d_in, const int* in_sizes, int n_in,
                              void* d_out, int out_size, void* d_ws, size_t ws_size,
                              hipStream_t stream) {
    const float* x = (const float*)d_in[0];
    const float* W = (const float*)d_in[1];
    const float* b = (const float*)d_in[2];
    const int* esrc = (const int*)d_in[3];
    const int* edst = (const int*)d_in[4];
    const float* ew = (const float*)d_in[5];
    int N = in_sizes[0] / IN_DIM;
    int E = in_sizes[3];
    int NB = (N + BKT_NODES - 1) >> BKT_SHIFT;  // 196

    char* p = (char*)d_ws;
    auto alloc = [&](size_t bytes) -> void* {
        void* r = (void*)p;
        p += (bytes + 255) & ~(size_t)255;
        return r;
    };
    unsigned short* hbf = (unsigned short*)alloc((size_t)N * EMB * 2);
    unsigned short* h1bf = (unsigned short*)alloc((size_t)N * EMB * 2);
    unsigned short* wtg = (unsigned short*)alloc((size_t)IN_DIM * EMB * 2);
    int* gcursor = (int*)alloc(256 * 4);
    int* row_ptr = (int*)alloc((size_t)(N + 1) * 4);
    int2* binned = (int2*)alloc((size_t)NB * SCAP * 8);
    int2* sorted = (int2*)alloc((size_t)E * 8);

    hipMemsetAsync(gcursor, 0, 256 * 4, stream);
    bin_scatter<<<(E + BINE - 1) / BINE, 256, 0, stream>>>(esrc, edst, ew, gcursor, binned, E, W, wtg);
    bucket_sort<<<NB, 1024, 0, stream>>>(binned, gcursor, sorted, row_ptr, N, E, NB);

    gemm_mfma<<<(N + 127) / 128, 256, 0, stream>>>(x, wtg, b, hbf, N);
    prop_g<1><<<(N + 3) / 4, 256, 0, stream>>>((const unsigned int*)hbf, h1bf, row_ptr, sorted, N);
    prop_g<0><<<(N + 3) / 4, 256, 0, stream>>>((const unsigned int*)h1bf, d_out, row_ptr, sorted, N);
}

// Round 21
// 222.715 us; speedup vs baseline: 1.0661x; 1.0492x over previous
//
#include <hip/hip_runtime.h>

#define IN_DIM 256
#define EMB 128
// bucket = dst >> 9 (512 nodes per bucket). Requires N <= 131072 (src packed in 17 bits).
#define BKT_SHIFT 9
#define BKT_NODES 512
#define BINE 4096       // edges per bin block (391 blocks)
#define SCAP 12288      // per-bucket region capacity (mean ~8192, +45 sigma)

typedef __attribute__((ext_vector_type(8))) short short8;
typedef __attribute__((ext_vector_type(4))) float f32x4;

__device__ __forceinline__ unsigned short bf16rtne(float f) {
    unsigned int u = __float_as_uint(f);
    return (unsigned short)((u + 0x7fffu + ((u >> 16) & 1u)) >> 16);
}

__device__ __forceinline__ unsigned int packbf2(float lo, float hi) {
    return ((unsigned int)bf16rtne(hi) << 16) | (unsigned int)bf16rtne(lo);
}

// packed f32x8 -> bf16x8 via native cvt_pk (RNE)
__device__ __forceinline__ short8 pack8(float4 f0, float4 f1) {
    union { uint4 u; short8 s; } U;
    asm("v_cvt_pk_bf16_f32 %0, %1, %2" : "=v"(U.u.x) : "v"(f0.x), "v"(f0.y));
    asm("v_cvt_pk_bf16_f32 %0, %1, %2" : "=v"(U.u.y) : "v"(f0.z), "v"(f0.w));
    asm("v_cvt_pk_bf16_f32 %0, %1, %2" : "=v"(U.u.z) : "v"(f1.x), "v"(f1.y));
    asm("v_cvt_pk_bf16_f32 %0, %1, %2" : "=v"(U.u.w) : "v"(f1.z), "v"(f1.w));
    return U.s;
}

// ---------------- CSR pass 1: per-block bucket histogram -> hm[block][256] ----------------
// No global atomics. Block 0 also casts W^T to bf16.

__global__ __launch_bounds__(512) void bin_hist(const int* __restrict__ dst,
                                                int* __restrict__ hm, int E,
                                                const float* __restrict__ W,
                                                unsigned short* __restrict__ wtg) {
    __shared__ int h[256];
    int t = threadIdx.x;
    if (blockIdx.x == 0) {
        for (int i = t; i < IN_DIM * EMB; i += 512) {
            int c = i & 127;
            int k = i >> 7;
            wtg[c * 256 + k] = bf16rtne(W[(size_t)k * 128 + c]);
        }
    }
    int e0 = blockIdx.x * BINE;
    int e1 = min(E, e0 + BINE);
    int n = e1 - e0;
    int ed[8];
    if (n == BINE) {
#pragma unroll
        for (int j = 0; j < 8; ++j) ed[j] = dst[e0 + t + j * 512];
    } else {
#pragma unroll
        for (int j = 0; j < 8; ++j) {
            int i = e0 + t + j * 512;
            ed[j] = (i < e1) ? dst[i] : -1;
        }
    }
    if (t < 256) h[t] = 0;
    __syncthreads();
#pragma unroll
    for (int j = 0; j < 8; ++j)
        if (ed[j] >= 0) atomicAdd(&h[ed[j] >> BKT_SHIFT], 1);
    __syncthreads();
    if (t < 256) hm[blockIdx.x * 256 + t] = h[t];
}

// ---------------- CSR pass 2: per-bucket column scan of hm (one block per bucket) ----
// hm[i][b] <- exclusive prefix over blocks; counts[b] <- total. No atomics.

__global__ __launch_bounds__(512) void col_scan(int* __restrict__ hm,
                                                int* __restrict__ counts, int nblk) {
    __shared__ int s[512];
    int b = blockIdx.x;
    int t = threadIdx.x;
    int v = (t < nblk) ? hm[t * 256 + b] : 0;
    s[t] = v;
    __syncthreads();
    for (int off = 1; off < 512; off <<= 1) {
        int u = (t >= off) ? s[t - off] : 0;
        __syncthreads();
        s[t] += u;
        __syncthreads();
    }
    if (t < nblk) hm[t * 256 + b] = s[t] - v;  // exclusive
    if (t == 511) counts[b] = s[511];          // total
}

// ---------------- CSR pass 3: scatter edges to deterministic slots ----------------
// lcur loaded from hm row (coalesced); LDS-only atomics; zero global atomics.

__global__ __launch_bounds__(512) void bin_scatter(const int* __restrict__ src,
                                                   const int* __restrict__ dst,
                                                   const float* __restrict__ w,
                                                   const int* __restrict__ hm,
                                                   int2* __restrict__ binned, int E) {
    __shared__ int lcur[256];
    int t = threadIdx.x;
    int e0 = blockIdx.x * BINE;
    int e1 = min(E, e0 + BINE);
    int n = e1 - e0;
    int ed[8], es[8];
    float ewv[8];
    if (n == BINE) {
#pragma unroll
        for (int j = 0; j < 8; ++j) {
            int i = e0 + t + j * 512;
            ed[j] = dst[i];
            es[j] = src[i];
            ewv[j] = w[i];
        }
    } else {
#pragma unroll
        for (int j = 0; j < 8; ++j) {
            int i = e0 + t + j * 512;
            if (i < e1) {
                ed[j] = dst[i];
                es[j] = src[i];
                ewv[j] = w[i];
            } else
                ed[j] = -1;
        }
    }
    if (t < 256) lcur[t] = hm[blockIdx.x * 256 + t];
    __syncthreads();
#pragma unroll
    for (int j = 0; j < 8; ++j) {
        if (ed[j] >= 0) {
            int b = ed[j] >> BKT_SHIFT;
            int p = atomicAdd(&lcur[b], 1);
            if (p < SCAP) {
                int2 r;
                r.x = es[j] | ((ed[j] & (BKT_NODES - 1)) << 17);
                r.y = __float_as_int(ewv[j]);
                binned[(size_t)b * SCAP + p] = r;
            }
        }
    }
}

// ---------------- CSR stage 2: per-bucket counting sort + inline global scan ----------------

__global__ __launch_bounds__(1024) void bucket_sort(const int2* __restrict__ binned,
                                                    const int* __restrict__ counts,
                                                    int2* __restrict__ sorted,
                                                    int* __restrict__ row_ptr,
                                                    int N, int E, int NB) {
    __shared__ int cnt[BKT_NODES];
    __shared__ int cur[BKT_NODES];
    __shared__ int scn[BKT_NODES];
    __shared__ int sc[256];
    __shared__ int begS, nS;
    __shared__ int2 stage[SCAP];  // 96 KB
    int t = threadIdx.x;
    int b = blockIdx.x;
    int node0 = b << BKT_SHIFT;
    int nn = min(BKT_NODES, N - node0);

    if (t < 256) sc[t] = (t < NB) ? min(counts[t], SCAP) : 0;
    __syncthreads();
    for (int off = 1; off < 256; off <<= 1) {
        int u = 0;
        if (t < 256 && t >= off) u = sc[t - off];
        __syncthreads();
        if (t < 256) sc[t] += u;
        __syncthreads();
    }
    if (t == 0) {
        int cb = min(counts[b], SCAP);
        begS = sc[b] - cb;
        nS = cb;
        if (b == 0) row_ptr[N] = E;
    }
    __syncthreads();
    int beg = begS;
    int n = nS;

    if (t < BKT_NODES) cnt[t] = 0;
    __syncthreads();
    const int2* bsrc = binned + (size_t)b * SCAP;
    for (int i = t; i < n; i += 1024) {
        int ld = ((unsigned int)bsrc[i].x) >> 17;
        atomicAdd(&cnt[ld], 1);
    }
    __syncthreads();
    int v = 0;
    if (t < BKT_NODES) {
        v = cnt[t];
        scn[t] = v;
    }
    __syncthreads();
    for (int off = 1; off < BKT_NODES; off <<= 1) {
        int u = 0;
        if (t < BKT_NODES && t >= off) u = scn[t - off];
        __syncthreads();
        if (t < BKT_NODES) scn[t] += u;
        __syncthreads();
    }
    if (t < BKT_NODES) {
        int excl = scn[t] - v;
        cur[t] = excl;
        if (t < nn) row_ptr[node0 + t] = beg + excl;
    }
    __syncthreads();
    for (int i = t; i < n; i += 1024) {
        int2 r = bsrc[i];
        int ld = ((unsigned int)r.x) >> 17;
        int p = atomicAdd(&cur[ld], 1);
        r.x &= 0x1FFFF;
        stage[p] = r;
    }
    __syncthreads();
    for (int i = t; i < n; i += 1024) sorted[beg + i] = stage[i];  // sequential
}

// ---------------- MFMA GEMM: h = relu(x@W + b), x f32 read directly ----------------

__global__ __launch_bounds__(256) void gemm_mfma(const float* __restrict__ x,
                                                 const unsigned short* __restrict__ wtg,
                                                 const float* __restrict__ bias,
                                                 unsigned short* __restrict__ hbf, int N) {
    __shared__ float Asf[128][64];          // 32 KB
    __shared__ unsigned short Bs[128][64];  // 16 KB
    int tid = threadIdx.x;
    int wv = tid >> 6;
    int lane = tid & 63;
    int lr = lane & 15;
    int lg = lane >> 4;
    int wr = wv * 32;
    int row0 = blockIdx.x * 128;

    f32x4 acc[2][8];
#pragma unroll
    for (int m = 0; m < 2; ++m)
#pragma unroll
        for (int n = 0; n < 8; ++n) acc[m][n] = (f32x4){0.f, 0.f, 0.f, 0.f};

    for (int kb = 0; kb < IN_DIM; kb += 64) {
#pragma unroll
        for (int i = 0; i < 8; ++i) {
            int p = 256 * i + wv * 64 + lane;
            int r = p >> 4;
            int c = p & 15;
            int gr = row0 + r;
            if (gr >= N) gr = N - 1;
            const float* ga = x + (size_t)gr * IN_DIM + kb + ((c ^ (r & 7)) << 2);
            __builtin_amdgcn_global_load_lds(
                (const __attribute__((address_space(1))) void*)ga,
                (__attribute__((address_space(3))) void*)((char*)&Asf[0][0] + (size_t)(256 * i + wv * 64) * 16),
                16, 0, 0);
        }
#pragma unroll
        for (int i = 0; i < 4; ++i) {
            int p = 256 * i + wv * 64 + lane;
            int r = p >> 3;
            int c = p & 7;
            const unsigned short* gb = wtg + (size_t)r * IN_DIM + kb + ((c ^ (r & 7)) * 8);
            __builtin_amdgcn_global_load_lds(
                (const __attribute__((address_space(1))) void*)gb,
                (__attribute__((address_space(3))) void*)((char*)&Bs[0][0] + (size_t)(256 * i + wv * 64) * 16),
                16, 0, 0);
        }
        __syncthreads();

        short8 a[2][2];
#pragma unroll
        for (int m = 0; m < 2; ++m)
#pragma unroll
            for (int kk = 0; kk < 2; ++kk) {
                int r = wr + m * 16 + lr;
                int s = r & 7;
                int ch0 = kk * 8 + lg * 2;
                float4 f0 = *(const float4*)&Asf[r][(ch0 ^ s) << 2];
                float4 f1 = *(const float4*)&Asf[r][((ch0 + 1) ^ s) << 2];
                a[m][kk] = pack8(f0, f1);
            }
#pragma unroll
        for (int n = 0; n < 8; ++n) {
            int cc = n * 16 + lr;
            int sw = cc & 7;
            short8 b0 = *(const short8*)&Bs[cc][(((0 * 4 + lg) ^ sw) * 8)];
            short8 b1 = *(const short8*)&Bs[cc][(((1 * 4 + lg) ^ sw) * 8)];
            acc[0][n] = __builtin_amdgcn_mfma_f32_16x16x32_bf16(a[0][0], b0, acc[0][n], 0, 0, 0);
            acc[0][n] = __builtin_amdgcn_mfma_f32_16x16x32_bf16(a[0][1], b1, acc[0][n], 0, 0, 0);
            acc[1][n] = __builtin_amdgcn_mfma_f32_16x16x32_bf16(a[1][0], b0, acc[1][n], 0, 0, 0);
            acc[1][n] = __builtin_amdgcn_mfma_f32_16x16x32_bf16(a[1][1], b1, acc[1][n], 0, 0, 0);
        }
        __syncthreads();
    }

#pragma unroll
    for (int n = 0; n < 8; ++n) {
        int c = n * 16 + lr;
        float bv = bias[c];
#pragma unroll
        for (int m = 0; m < 2; ++m) {
#pragma unroll
            for (int j = 0; j < 4; ++j) {
                int r = row0 + wr + m * 16 + lg * 4 + j;
                if (r < N) {
                    float v = fmaxf(acc[m][n][j] + bv, 0.f);
                    hbf[(size_t)r * EMB + c] = bf16rtne(v);
                }
            }
        }
    }
}

// ---------------- propagation: wave per node, readlane broadcasts, 16-deep gathers ----

template <int OUTBF>
__global__ __launch_bounds__(256) void prop_g(const unsigned int* __restrict__ hin,
                                              void* __restrict__ hout,
                                              const int* __restrict__ rp,
                                              const int2* __restrict__ rec, int N) {
    int wvid = threadIdx.x >> 6;
    int lane = threadIdx.x & 63;
    int node = blockIdx.x * 4 + wvid;
    if (node >= N) return;
    int beg = __builtin_amdgcn_readfirstlane(rp[node]);
    int end = __builtin_amdgcn_readfirstlane(rp[node + 1]);
    float ax = 0.f, ay = 0.f;
    for (int c0 = beg; c0 < end; c0 += 64) {
        int cnt = end - c0;
        if (cnt > 64) cnt = 64;
        int li = lane < cnt ? lane : 0;
        int2 r = rec[c0 + li];
        for (int jb = 0; jb < cnt; jb += 16) {
            int ssrc[16];
            float sw[16];
#pragma unroll
            for (int k = 0; k < 16; ++k) {
                int jj = jb + k;
                int jc = jj < cnt ? jj : 0;
                ssrc[k] = __builtin_amdgcn_readlane(r.x, jc);
                float wv = __uint_as_float((unsigned int)__builtin_amdgcn_readlane(r.y, jc));
                sw[k] = (jj < cnt) ? wv : 0.f;
            }
            unsigned int g[16];
#pragma unroll
            for (int k = 0; k < 16; ++k) g[k] = hin[(size_t)ssrc[k] * 64 + lane];
#pragma unroll
            for (int k = 0; k < 16; ++k) {
                ax = fmaf(sw[k], __uint_as_float(g[k] << 16), ax);
                ay = fmaf(sw[k], __uint_as_float(g[k] & 0xffff0000u), ay);
            }
        }
    }
    if (OUTBF) {
        ((unsigned int*)hout)[(size_t)node * 64 + lane] = packbf2(ax, ay);
    } else {
        float2 o;
        o.x = ax;
        o.y = ay;
        ((float2*)hout)[(size_t)node * 64 + lane] = o;
    }
}

// ---------------- launch ----------------

extern "C" void kernel_launch(void* const* d_in, const int* in_sizes, int n_in,
                              void* d_out, int out_size, void* d_ws, size_t ws_size,
                              hipStream_t stream) {
    const float* x = (const float*)d_in[0];
    const float* W = (const float*)d_in[1];
    const float* b = (const float*)d_in[2];
    const int* esrc = (const int*)d_in[3];
    const int* edst = (const int*)d_in[4];
    const float* ew = (const float*)d_in[5];
    int N = in_sizes[0] / IN_DIM;
    int E = in_sizes[3];
    int NB = (N + BKT_NODES - 1) >> BKT_SHIFT;  // 196
    int nblk = (E + BINE - 1) / BINE;           // 391 (must be <= 512)

    char* p = (char*)d_ws;
    auto alloc = [&](size_t bytes) -> void* {
        void* r = (void*)p;
        p += (bytes + 255) & ~(size_t)255;
        return r;
    };
    unsigned short* hbf = (unsigned short*)alloc((size_t)N * EMB * 2);
    unsigned short* h1bf = (unsigned short*)alloc((size_t)N * EMB * 2);
    unsigned short* wtg = (unsigned short*)alloc((size_t)IN_DIM * EMB * 2);
    int* counts = (int*)alloc(256 * 4);
    int* row_ptr = (int*)alloc((size_t)(N + 1) * 4);
    int* hm = (int*)alloc((size_t)nblk * 256 * 4);
    int2* binned = (int2*)alloc((size_t)NB * SCAP * 8);
    int2* sorted = (int2*)alloc((size_t)E * 8);

    bin_hist<<<nblk, 512, 0, stream>>>(edst, hm, E, W, wtg);
    col_scan<<<256, 512, 0, stream>>>(hm, counts, nblk);
    bin_scatter<<<nblk, 512, 0, stream>>>(esrc, edst, ew, hm, binned, E);
    bucket_sort<<<NB, 1024, 0, stream>>>(binned, counts, sorted, row_ptr, N, E, NB);

    gemm_mfma<<<(N + 127) / 128, 256, 0, stream>>>(x, wtg, b, hbf, N);
    prop_g<1><<<(N + 3) / 4, 256, 0, stream>>>((const unsigned int*)hbf, h1bf, row_ptr, sorted, N);
    prop_g<0><<<(N + 3) / 4, 256, 0, stream>>>((const unsigned int*)h1bf, d_out, row_ptr, sorted, N);
}